// Round 8
// baseline (303.498 us; speedup 1.0000x reference)
//
#include <hip/hip_runtime.h>

// ---------------------------------------------------------------------------
// TiedRowAxialAttention on MI355X (gfx950), bf16 MFMA pipeline.
// dims: b=4 rows=64 t=256 dim=512 heads=8 dim_head=64 ; scale = 1/64
// stages:
//   prep:   x->bf16 ; W_qkv permuted (d,k,h)->(k,h,d) + bf16 ; W0->bf16
//   gemm1:  qkv = x @ Wp^T (M=65536,N=1536,K=512) -> Q[bh][i][rd], K[bh][j][rd],
//           Vt[bh][rd][j]
//   gemm_s: S[bh][i][j] = sum_rd Q K (batched NT, split-K=8, fp32 partials)
//   softmax: wave-per-row, P = softmax(S/64) bf16 (rinv folded in)
//   gemm_pv: O = P V via A=Vt,B=P (M=4096 rd, N=256 i, K=256) -> O2[(b,r,i)][hd]
//   gemm2:  out = O2 @ W0^T -> fp32
// Shared mainloop: 256x128 tile, BK=32, 4 waves (2Mx2N), per-wave 128x64
// (acc[8][4]), 3 LDS buffers (72 KB) -> 2 blocks/CU, 2-tile prefetch lead,
// counted vmcnt(6), one barrier per K-tile. NO forced lgkm drain: plain-C++
// LDS loads let the compiler emit fine-grained lgkmcnt and pipeline ds_read
// into the MFMA burst (m97 mechanism; R6's forced drain was the 35% ceiling).
// ---------------------------------------------------------------------------

typedef short  bf16x8 __attribute__((ext_vector_type(8)));
typedef float  f32x4  __attribute__((ext_vector_type(4)));

#define MFMA16(a,b,c) __builtin_amdgcn_mfma_f32_16x16x32_bf16((a),(b),(c),0,0,0)

__device__ __forceinline__ ushort f2bf(float f) {
  union { float f; unsigned u; } v; v.f = f;
  unsigned r = v.u + 0x7fffu + ((v.u >> 16) & 1u);   // RNE
  return (ushort)(r >> 16);
}

__device__ __forceinline__ void gload_lds16(const void* g, void* lds) {
  __builtin_amdgcn_global_load_lds(
      (const __attribute__((address_space(1))) void*)g,
      (__attribute__((address_space(3))) void*)lds, 16, 0, 0);
}

// -------------------------------- prep -------------------------------------

__global__ void cast_f32_to_bf16(const float* __restrict__ in,
                                 ushort* __restrict__ out, int n4) {
  int idx = blockIdx.x * blockDim.x + threadIdx.x;
  int stride = gridDim.x * blockDim.x;
  for (int v = idx; v < n4; v += stride) {
    float4 f = reinterpret_cast<const float4*>(in)[v];
    ushort4 o; o.x = f2bf(f.x); o.y = f2bf(f.y); o.z = f2bf(f.z); o.w = f2bf(f.w);
    reinterpret_cast<ushort4*>(out)[v] = o;
  }
}

// Wp[n'][c], n' = (k*8+h)*64+d  <-  W_qkv[d*24+k*8+h][c]
__global__ void permute_wqkv_k(const float* __restrict__ W, ushort* __restrict__ Wp) {
  int np = blockIdx.x;                    // 0..1535
  int k = np >> 9, h = (np >> 6) & 7, d = np & 63;
  const float4* s = reinterpret_cast<const float4*>(W + (size_t)(d * 24 + k * 8 + h) * 512);
  ushort4* o = reinterpret_cast<ushort4*>(Wp + (size_t)np * 512);
  for (int c = threadIdx.x; c < 128; c += blockDim.x) {
    float4 f = s[c];
    ushort4 u; u.x = f2bf(f.x); u.y = f2bf(f.y); u.z = f2bf(f.z); u.w = f2bf(f.w);
    o[c] = u;
  }
}

// ================== 256x128 pipelined NT mainloop (4 waves) =================
// C = A @ B^T ; A [M][lda], B [N][ldb] bf16 row-major, K = 32*P.
// 256 threads = 4 waves (2M x 2N), per-wave 128x64 out = acc[8][4] 16x16 frags.
// BK=32, 3 LDS buffers (A 16KB + B 8KB each = 24KB), 2-tile prefetch lead,
// counted vmcnt(6) once per K-tile, one barrier per K-tile.
// LDS per-row slot rotation: storage slot t at row r holds k-slot (t - r>>1)&3
// (stage source pre-rotated; reads use slot (kl + r>>1)&3) -> conflict-free.

__device__ __forceinline__ void gemm_nt_256x128(
    const ushort* __restrict__ A, const ushort* __restrict__ B,
    int lda, int ldb, int P, int m0, int n0, char* lds, f32x4 (&acc)[8][4]) {
  const int tid = threadIdx.x;
  const int w = tid >> 6, l = tid & 63;
  const int il = l & 15, kl = l >> 4;
  const int wm = w >> 1, wn = w & 1;

  auto stageA = [&](char* buf, int kt) {
#pragma unroll
    for (int c = 0; c < 4; ++c) {
      int rbase = (w << 6) + (c << 4);                     // wave-uniform
      int row = rbase + (l >> 2);
      int s = ((l & 3) - ((row >> 1) & 3)) & 3;
      gload_lds16(A + (size_t)(m0 + row) * lda + (kt << 5) + (s << 3),
                  buf + rbase * 64);
    }
  };
  auto stageB = [&](char* buf, int kt) {
#pragma unroll
    for (int c = 0; c < 2; ++c) {
      int rbase = (w << 5) + (c << 4);                     // wave-uniform
      int row = rbase + (l >> 2);
      int s = ((l & 3) - ((row >> 1) & 3)) & 3;
      gload_lds16(B + (size_t)(n0 + row) * ldb + (kt << 5) + (s << 3),
                  buf + 16384 + rbase * 64);
    }
  };
  auto loadA8 = [&](const char* buf, bf16x8 (&af)[8]) {
#pragma unroll
    for (int q = 0; q < 8; ++q) {
      int row = (wm << 7) + (q << 4) + il;
      af[q] = *(const bf16x8*)(buf + row * 64 + (((kl + (row >> 1)) & 3) << 4));
    }
  };
  auto loadB4 = [&](const char* buf, bf16x8 (&bfr)[4]) {
#pragma unroll
    for (int q = 0; q < 4; ++q) {
      int row = (wn << 6) + (q << 4) + il;
      bfr[q] = *(const bf16x8*)(buf + 16384 + row * 64 + (((kl + (row >> 1)) & 3) << 4));
    }
  };

#pragma unroll
  for (int i = 0; i < 8; ++i)
#pragma unroll
    for (int j = 0; j < 4; ++j) acc[i][j] = f32x4{0.f, 0.f, 0.f, 0.f};

  // prologue: stage tiles 0,1 (6 vmem ops each); t0 must be resident.
  stageA(lds, 0);         stageB(lds, 0);
  stageA(lds + 24576, 1); stageB(lds + 24576, 1);
  asm volatile("s_waitcnt vmcnt(6)" ::: "memory");
  __builtin_amdgcn_s_barrier();

  int cur = 0, nx = 2;
  for (int g = 0; g < P; ++g) {
    char* cbuf = lds + cur * 24576;
    char* sbuf = lds + nx * 24576;
    bf16x8 af[8], bfr[4];
    loadA8(cbuf, af);
    loadB4(cbuf, bfr);
    if (g + 2 < P) { stageA(sbuf, g + 2); stageB(sbuf, g + 2); }
    // No forced lgkm drain here: compiler emits fine-grained lgkmcnt so the
    // later ds_reads complete under the earlier MFMAs.
    __builtin_amdgcn_s_setprio(1);
#pragma unroll
    for (int fm = 0; fm < 8; ++fm)
#pragma unroll
      for (int fn = 0; fn < 4; ++fn)
        acc[fm][fn] = MFMA16(af[fm], bfr[fn], acc[fm][fn]);
    __builtin_amdgcn_s_setprio(0);
    if (g + 2 < P) asm volatile("s_waitcnt vmcnt(6)" ::: "memory");
    else           asm volatile("s_waitcnt vmcnt(0)" ::: "memory");
    __builtin_amdgcn_s_barrier();
    cur = (cur == 2) ? 0 : cur + 1;
    nx  = (nx  == 2) ? 0 : nx  + 1;
  }
}

// ------------------------------- gemm1 (qkv) --------------------------------
// 3072 blocks; XCD swizzle: the 12 n-tiles of one A-panel group stay together.

__global__ __launch_bounds__(256, 2) void gemm_qkv_k(
    const ushort* __restrict__ xb, const ushort* __restrict__ Wp,
    ushort* __restrict__ Qb, ushort* __restrict__ Kb, ushort* __restrict__ Vt) {
  __shared__ __align__(16) char lds[73728];
  f32x4 acc[8][4];
  const int Bid = blockIdx.x;
  const int xcd = Bid & 7, idx = Bid >> 3;
  const int nt = idx % 12, pl = idx / 12;       // pl 0..31
  const int m0 = ((pl << 3) + xcd) << 8;        // 256 m-tiles * 256
  const int n0 = nt << 7;
  gemm_nt_256x128(xb, Wp, 512, 512, 16, m0, n0, lds, acc);

  const int tid = threadIdx.x, w = tid >> 6, l = tid & 63;
  const int il = l & 15, kl = l >> 4;
  const int wm = w >> 1, wn = w & 1;
  const int kq = n0 >> 9;                       // block-uniform: 0=Q 1=K 2=V
  const int br = m0 >> 8, b = br >> 6, r = br & 63;   // one (b,r) per block

  if (kq < 2) {
    ushort* dstb = kq ? Kb : Qb;
#pragma unroll
    for (int fm = 0; fm < 8; ++fm)
#pragma unroll
      for (int fn = 0; fn < 4; ++fn) {
        int n = n0 + (wn << 6) + (fn << 4) + il;
        int h = (n >> 6) & 7, d = n & 63;
#pragma unroll
        for (int j = 0; j < 4; ++j) {
          int i = (wm << 7) + (fm << 4) + (kl << 2) + j;
          size_t dst = ((size_t)((((b << 3) + h) << 8) + i) << 12) + (r << 6) + d;
          dstb[dst] = f2bf(acc[fm][fn][j]);     // lanes: 2B x16 contiguous in d
        }
      }
  } else {
#pragma unroll
    for (int fm = 0; fm < 8; ++fm)
#pragma unroll
      for (int fn = 0; fn < 4; ++fn) {
        int n = n0 - 1024 + (wn << 6) + (fn << 4) + il;     // h*64+d
        int h = n >> 6, d = n & 63;
        int i0 = (wm << 7) + (fm << 4) + (kl << 2);
        size_t dst = (((size_t)((((b << 3) + h) << 12)) + (r << 6) + d) << 8) + i0;
        ushort4 pk; pk.x = f2bf(acc[fm][fn][0]); pk.y = f2bf(acc[fm][fn][1]);
        pk.z = f2bf(acc[fm][fn][2]); pk.w = f2bf(acc[fm][fn][3]);
        *reinterpret_cast<ushort4*>(&Vt[dst]) = pk;   // 4 consecutive i
      }
  }
}

// ------------------------------- gemm2 (out) --------------------------------
// 1024 blocks; XCD swizzle; scalar f32 stores (lanes 4B x16 contiguous).

__global__ __launch_bounds__(256, 2) void gemm_out_k(
    const ushort* __restrict__ O2, const ushort* __restrict__ W0b,
    float* __restrict__ out) {
  __shared__ __align__(16) char lds[73728];
  f32x4 acc[8][4];
  const int Bid = blockIdx.x;
  const int xcd = Bid & 7, idx = Bid >> 3;
  const int nt = idx & 3, pl = idx >> 2;        // pl 0..31
  const int m0 = ((pl << 3) + xcd) << 8;
  const int n0 = nt << 7;
  gemm_nt_256x128(O2, W0b, 512, 512, 16, m0, n0, lds, acc);

  const int tid = threadIdx.x, w = tid >> 6, l = tid & 63;
  const int il = l & 15, kl = l >> 4;
  const int wm = w >> 1, wn = w & 1;
#pragma unroll
  for (int fm = 0; fm < 8; ++fm)
#pragma unroll
    for (int fn = 0; fn < 4; ++fn) {
      int n = n0 + (wn << 6) + (fn << 4) + il;
#pragma unroll
      for (int j = 0; j < 4; ++j) {
        int m = m0 + (wm << 7) + (fm << 4) + (kl << 2) + j;
        out[(size_t)m * 512 + n] = acc[fm][fn][j];
      }
    }
}

// ---------------------- gemm_s: S partials (split-K=8) ----------------------
// 512 blocks; z = bh*8+ks, each computes a 256x128 slab of S over rd-range
// ks*512..+512. Sp[z][i][j] fp32.

__global__ __launch_bounds__(256, 2) void gemm_s_k(
    const ushort* __restrict__ Qb, const ushort* __restrict__ Kb,
    float* __restrict__ Sp) {
  __shared__ __align__(16) char lds[73728];
  f32x4 acc[8][4];
  const int Bid = blockIdx.x;
  const int xcd = Bid & 7, idx = Bid >> 3;      // idx 0..63
  const int nt = idx & 1, zl = idx >> 1;        // zl 0..31
  const int z = (zl << 3) + xcd;                // 0..255
  const int bh = z >> 3, ks = z & 7;
  const int n0 = nt << 7;
  const size_t base = ((size_t)bh << 20) + ((size_t)ks << 9);
  gemm_nt_256x128(Qb + base, Kb + base, 4096, 4096, 16, 0, n0, lds, acc);

  const int tid = threadIdx.x, w = tid >> 6, l = tid & 63;
  const int il = l & 15, kl = l >> 4;
  const int wm = w >> 1, wn = w & 1;
  float* o = Sp + ((size_t)z << 16);
#pragma unroll
  for (int fm = 0; fm < 8; ++fm)
#pragma unroll
    for (int fn = 0; fn < 4; ++fn) {
      int n = n0 + (wn << 6) + (fn << 4) + il;
#pragma unroll
      for (int j = 0; j < 4; ++j) {
        int m = (wm << 7) + (fm << 4) + (kl << 2) + j;
        o[(size_t)m * 256 + n] = acc[fm][fn][j];
      }
    }
}

// ------------------------- softmax (wave per row) ---------------------------
// P[bh][i][j] = softmax_j(sum_{ks=0..7} Sp[8bh+ks] / 64), bf16 with 1/sum.

__global__ void softmax_k(const float* __restrict__ Sp, ushort* __restrict__ Pb) {
  const int w = threadIdx.x >> 6, l = threadIdx.x & 63;
  const int row = (blockIdx.x << 2) + w;        // 0..8191
  const int bh = row >> 8, i = row & 255;
  const float4* p0 = reinterpret_cast<const float4*>(
      Sp + (((size_t)bh << 3) << 16) + ((size_t)i << 8)) + l;
  float s0 = 0.f, s1 = 0.f, s2 = 0.f, s3 = 0.f;
#pragma unroll
  for (int ks = 0; ks < 8; ++ks) {
    float4 a = p0[(size_t)ks * 16384];
    s0 += a.x; s1 += a.y; s2 += a.z; s3 += a.w;
  }
  const float scale = 0.015625f;
  s0 *= scale; s1 *= scale; s2 *= scale; s3 *= scale;
  float m = fmaxf(fmaxf(s0, s1), fmaxf(s2, s3));
#pragma unroll
  for (int d2 = 1; d2 < 64; d2 <<= 1) m = fmaxf(m, __shfl_xor(m, d2));
  float e0 = __expf(s0 - m), e1 = __expf(s1 - m);
  float e2 = __expf(s2 - m), e3 = __expf(s3 - m);
  float sum = e0 + e1 + e2 + e3;
#pragma unroll
  for (int d2 = 1; d2 < 64; d2 <<= 1) sum += __shfl_xor(sum, d2);
  float r = 1.0f / sum;
  ushort4 p; p.x = f2bf(e0 * r); p.y = f2bf(e1 * r);
  p.z = f2bf(e2 * r); p.w = f2bf(e3 * r);
  reinterpret_cast<ushort4*>(Pb + ((size_t)bh << 16) + ((size_t)i << 8))[l] = p;
}

// ---------------------- gemm_pv: O = P V  (A=Vt, B=P) -----------------------
// 1024 blocks; XCD swizzle groups one bh's 32 blocks on one XCD.
// M=4096 (rd), N=256 (i), K=256. Writes O2[(b,r,i)][h*64+d] as ushort4.

__global__ __launch_bounds__(256, 2) void gemm_pv_k(
    const ushort* __restrict__ Vt, const ushort* __restrict__ Pb,
    ushort* __restrict__ O2) {
  __shared__ __align__(16) char lds[73728];
  f32x4 acc[8][4];
  const int Bid = blockIdx.x;
  const int xcd = Bid & 7, idx = Bid >> 3;      // idx 0..127
  const int sub = idx & 31, grp = idx >> 5;     // sub: mt*2+nt, grp 0..3
  const int bh = (grp << 3) + xcd, b = bh >> 3, h = bh & 7;
  const int m0 = (sub >> 1) << 8;               // rd tile (16 x 256)
  const int n0 = (sub & 1) << 7;                // i tile (2 x 128)
  gemm_nt_256x128(Vt + ((size_t)bh << 20), Pb + ((size_t)bh << 16),
                  256, 256, 8, m0, n0, lds, acc);

  const int tid = threadIdx.x, w = tid >> 6, l = tid & 63;
  const int il = l & 15, kl = l >> 4;
  const int wm = w >> 1, wn = w & 1;
#pragma unroll
  for (int fm = 0; fm < 8; ++fm) {
    int rd0 = m0 + (wm << 7) + (fm << 4) + (kl << 2);
    int r = rd0 >> 6, d0 = rd0 & 63;
#pragma unroll
    for (int fn = 0; fn < 4; ++fn) {
      int i = n0 + (wn << 6) + (fn << 4) + il;
      ushort4 pk; pk.x = f2bf(acc[fm][fn][0]); pk.y = f2bf(acc[fm][fn][1]);
      pk.z = f2bf(acc[fm][fn][2]); pk.w = f2bf(acc[fm][fn][3]);
      *reinterpret_cast<ushort4*>(
          O2 + ((size_t)((((b << 6) + r) << 8) + i) << 9) + (h << 6) + d0) = pk;
    }
  }
}

// ------------------------------- launcher -----------------------------------

extern "C" void kernel_launch(void* const* d_in, const int* in_sizes, int n_in,
                              void* d_out, int out_size, void* d_ws, size_t ws_size,
                              hipStream_t stream) {
  const float* x    = (const float*)d_in[0];
  const float* Wqkv = (const float*)d_in[1];
  const float* W0   = (const float*)d_in[2];
  float* out = (float*)d_out;

  char* ws = (char*)d_ws;
  ushort* xb  = (ushort*)(ws);                    // 67,108,864 B (-> Sp -> O2)
  ushort* Wp  = (ushort*)(ws + 67108864);         //  1,572,864
  ushort* W0b = (ushort*)(ws + 68681728);         //    524,288
  ushort* Qb  = (ushort*)(ws + 69206016);         // 67,108,864 (-> Pb)
  ushort* Kb  = (ushort*)(ws + 136314880);        // 67,108,864
  ushort* Vt  = (ushort*)(ws + 203423744);        // 67,108,864  -> total 270,532,608
  if (ws_size < 270532608ull) return;             // workspace too small: fail visibly

  cast_f32_to_bf16<<<2048, 256, 0, stream>>>(x, xb, 8388608);
  cast_f32_to_bf16<<<256, 256, 0, stream>>>(W0, W0b, 65536);
  permute_wqkv_k<<<1536, 128, 0, stream>>>(Wqkv, Wp);

  gemm_qkv_k<<<3072, 256, 0, stream>>>(xb, Wp, Qb, Kb, Vt);

  float*  Sp = (float*)xb;                        // xb dead after gemm1 (64 MB)
  ushort* Pb = Qb;                                // Qb dead after gemm_s (8.4 MB)
  ushort* O2 = xb;                                // Sp dead after softmax (64 MB)

  gemm_s_k<<<512, 256, 0, stream>>>(Qb, Kb, Sp);
  softmax_k<<<2048, 256, 0, stream>>>(Sp, Pb);
  gemm_pv_k<<<1024, 256, 0, stream>>>(Vt, Pb, O2);

  gemm_out_k<<<1024, 256, 0, stream>>>(O2, W0b, out);
}

// Round 9
// 300.936 us; speedup vs baseline: 1.0085x; 1.0085x over previous
//
#include <hip/hip_runtime.h>

// ---------------------------------------------------------------------------
// TiedRowAxialAttention on MI355X (gfx950), bf16 MFMA pipeline.
// dims: b=4 rows=64 t=256 dim=512 heads=8 dim_head=64 ; scale = 1/64
// stages:
//   prep:   x->bf16 ; W_qkv permuted (d,k,h)->(k,h,d) + bf16 ; W0->bf16
//   gemm1:  qkv = x @ Wp^T -> Q[bh][i][rd], K[bh][j][rd], Vt[bh][rd][j]
//   gemm_s: S[bh][i][j] = sum_rd Q K (batched NT, split-K=8, fp32 partials)
//   softmax: wave-per-row, P = softmax(S/64) bf16 (rinv folded in)
//   gemm_pv: O = P V via A=Vt,B=P -> O2[(b,r,i)][hd]
//   gemm2:  out = O2 @ W0^T -> fp32
// All GEMMs: 8-phase pipelined mainloop. 256x256 tile, BK=64, 8 waves
// (2Mx4N, per-wave 128x64, acc[8][4]). 2 x 64KB LDS dbuf. Per K-tile =
// 4 phases {ds_read || stage 16KB unit ; BAR ; 16 MFMA ; BAR}; staging ring
// refills slots freed by the previous phase (barrier-ordered => race-free);
// counted vmcnt(4) once per K-tile (never 0 in steady state).
// 8-slot LDS rotation swizzle (slot t at row r holds k-slot (t-r)&7),
// conflict-free for quarter-wave groups (measured 0 conflicts for the
// 4-slot analog in R5-R7).
// ---------------------------------------------------------------------------

typedef short  bf16x8 __attribute__((ext_vector_type(8)));
typedef float  f32x4  __attribute__((ext_vector_type(4)));

#define MFMA16(a,b,c) __builtin_amdgcn_mfma_f32_16x16x32_bf16((a),(b),(c),0,0,0)

__device__ __forceinline__ ushort f2bf(float f) {
  union { float f; unsigned u; } v; v.f = f;
  unsigned r = v.u + 0x7fffu + ((v.u >> 16) & 1u);   // RNE
  return (ushort)(r >> 16);
}

__device__ __forceinline__ void gload_lds16(const void* g, void* lds) {
  __builtin_amdgcn_global_load_lds(
      (const __attribute__((address_space(1))) void*)g,
      (__attribute__((address_space(3))) void*)lds, 16, 0, 0);
}

// -------------------------------- prep -------------------------------------

__global__ void cast_f32_to_bf16(const float* __restrict__ in,
                                 ushort* __restrict__ out, int n4) {
  int idx = blockIdx.x * blockDim.x + threadIdx.x;
  int stride = gridDim.x * blockDim.x;
  for (int v = idx; v < n4; v += stride) {
    float4 f = reinterpret_cast<const float4*>(in)[v];
    ushort4 o; o.x = f2bf(f.x); o.y = f2bf(f.y); o.z = f2bf(f.z); o.w = f2bf(f.w);
    reinterpret_cast<ushort4*>(out)[v] = o;
  }
}

// Wp[n'][c], n' = (k*8+h)*64+d  <-  W_qkv[d*24+k*8+h][c]
__global__ void permute_wqkv_k(const float* __restrict__ W, ushort* __restrict__ Wp) {
  int np = blockIdx.x;                    // 0..1535
  int k = np >> 9, h = (np >> 6) & 7, d = np & 63;
  const float4* s = reinterpret_cast<const float4*>(W + (size_t)(d * 24 + k * 8 + h) * 512);
  ushort4* o = reinterpret_cast<ushort4*>(Wp + (size_t)np * 512);
  for (int c = threadIdx.x; c < 128; c += blockDim.x) {
    float4 f = s[c];
    ushort4 u; u.x = f2bf(f.x); u.y = f2bf(f.y); u.z = f2bf(f.z); u.w = f2bf(f.w);
    o[c] = u;
  }
}

// ================= 256x256 8-phase pipelined NT mainloop ====================
// C = A @ B^T ; A [M][lda], B [N][ldb] bf16 row-major, K = 64*NT (NT >= 4).
// 512 threads = 8 waves (2M x 4N), per-wave 128x64 out = acc[8][4].
// LDS: 2 buffers x (A 32KB + B 32KB). Phase q of K-tile g (q=0..3):
//   h=q>>1 selects A row-bands (fr 4h..4h+3), c=q&1 selects B col-pair
//   (fn 2c,2c+1); A regs reused across (q, q+1), B regs across (q, q+2).
// Staging per phase = one 16KB unit (2 gload rounds/thread):
//   ph0: Bb1(kt g+1) -> other buf ; ph1: Ah0(g+2) ; ph2: Bb0(g+2) ;
//   ph3: Ah1(g+2) -> own buf (slots last read the previous phase).
// vmcnt(4) at each K-tile end; vmcnt(0) only when pipeline winds down.

__device__ __forceinline__ void gemm_nt_8phase(
    const ushort* __restrict__ A, const ushort* __restrict__ B,
    int lda, int ldb, int NT, int m0, int n0, char* lds, f32x4 (&acc)[8][4]) {
  const int tid = threadIdx.x;
  const int w = tid >> 6, l = tid & 63;
  const int il = l & 15, kl = l >> 4;
  const int wm = w >> 2, wn = w & 3;

  // ---- staging: one 16KB unit = 2 gload rounds -----------------------------
  auto stageA = [&](char* buf, int kt, int h) {
#pragma unroll
    for (int hh = 0; hh < 2; ++hh) {
      int rbase = (hh << 7) + (h << 6) + (w << 3);        // wave-uniform
      int row = rbase + (l >> 3);
      int ks = ((l & 7) - row) & 7;
      gload_lds16(A + (size_t)(m0 + row) * lda + (kt << 6) + (ks << 3),
                  buf + (size_t)rbase * 128);
    }
  };
  auto stageB = [&](char* buf, int kt, int c) {
#pragma unroll
    for (int c2 = 0; c2 < 2; ++c2) {
      int rr = (w << 3);                                  // wave-uniform part
      int rbase = (c2 << 7) + (((rr >> 5)) << 6) + (c << 5) + (rr & 31);
      int row = rbase + (l >> 3);
      int ks = ((l & 7) - row) & 7;
      gload_lds16(B + (size_t)(n0 + row) * ldb + (kt << 6) + (ks << 3),
                  buf + 32768 + (size_t)rbase * 128);
    }
  };
  // ---- register fragment loads --------------------------------------------
  auto loadA = [&](const char* buf, int h, bf16x8 (&a)[4][2]) {
#pragma unroll
    for (int fr4 = 0; fr4 < 4; ++fr4)
#pragma unroll
      for (int kk = 0; kk < 2; ++kk) {
        int row = (wm << 7) + (((h << 2) + fr4) << 4) + il;
        a[fr4][kk] = *(const bf16x8*)(buf + row * 128 +
                        ((((kk << 2) + kl + row) & 7) << 4));
      }
  };
  auto loadB = [&](const char* buf, int c, bf16x8 (&bb)[2][2]) {
#pragma unroll
    for (int fn2 = 0; fn2 < 2; ++fn2)
#pragma unroll
      for (int kk = 0; kk < 2; ++kk) {
        int row = (wn << 6) + (((c << 1) + fn2) << 4) + il;
        bb[fn2][kk] = *(const bf16x8*)(buf + 32768 + row * 128 +
                        ((((kk << 2) + kl + row) & 7) << 4));
      }
  };

#pragma unroll
  for (int i = 0; i < 8; ++i)
#pragma unroll
    for (int j = 0; j < 4; ++j) acc[i][j] = f32x4{0.f, 0.f, 0.f, 0.f};

  char* buf0 = lds;
  char* buf1 = lds + 65536;

  // prologue: kt0 full (8 loads) + kt1 {Ah0,Bb0,Ah1} (6 loads)
  stageA(buf0, 0, 0); stageB(buf0, 0, 0); stageA(buf0, 0, 1); stageB(buf0, 0, 1);
  stageA(buf1, 1, 0); stageB(buf1, 1, 0); stageA(buf1, 1, 1);
  asm volatile("s_waitcnt vmcnt(6)" ::: "memory");
  __builtin_amdgcn_s_barrier();

  for (int g = 0; g < NT; ++g) {
    char* bc = lds + ((g & 1) << 16);
    char* bo = lds + (((g & 1) ^ 1) << 16);
    bf16x8 a[4][2], b0[2][2], b1[2][2];

    // ---- phase 0: MFMA h0/c0 ; stage Bb1(kt g+1) -> other buf ----
    loadA(bc, 0, a);
    loadB(bc, 0, b0);
    if (g + 1 < NT) stageB(bo, g + 1, 1);
    __builtin_amdgcn_s_barrier();
    __builtin_amdgcn_s_setprio(1);
#pragma unroll
    for (int fr4 = 0; fr4 < 4; ++fr4)
#pragma unroll
      for (int fn2 = 0; fn2 < 2; ++fn2)
#pragma unroll
        for (int kk = 0; kk < 2; ++kk)
          acc[fr4][fn2] = MFMA16(a[fr4][kk], b0[fn2][kk], acc[fr4][fn2]);
    __builtin_amdgcn_s_setprio(0);
    __builtin_amdgcn_s_barrier();

    // ---- phase 1: MFMA h0/c1 ; stage Ah0(kt g+2) -> own buf ----
    loadB(bc, 1, b1);
    if (g + 2 < NT) stageA(bc, g + 2, 0);
    __builtin_amdgcn_s_barrier();
    __builtin_amdgcn_s_setprio(1);
#pragma unroll
    for (int fr4 = 0; fr4 < 4; ++fr4)
#pragma unroll
      for (int fn2 = 0; fn2 < 2; ++fn2)
#pragma unroll
        for (int kk = 0; kk < 2; ++kk)
          acc[fr4][2 + fn2] = MFMA16(a[fr4][kk], b1[fn2][kk], acc[fr4][2 + fn2]);
    __builtin_amdgcn_s_setprio(0);
    __builtin_amdgcn_s_barrier();

    // ---- phase 2: MFMA h1/c0 ; stage Bb0(kt g+2) ----
    loadA(bc, 1, a);
    if (g + 2 < NT) stageB(bc, g + 2, 0);
    __builtin_amdgcn_s_barrier();
    __builtin_amdgcn_s_setprio(1);
#pragma unroll
    for (int fr4 = 0; fr4 < 4; ++fr4)
#pragma unroll
      for (int fn2 = 0; fn2 < 2; ++fn2)
#pragma unroll
        for (int kk = 0; kk < 2; ++kk)
          acc[4 + fr4][fn2] = MFMA16(a[fr4][kk], b0[fn2][kk], acc[4 + fr4][fn2]);
    __builtin_amdgcn_s_setprio(0);
    __builtin_amdgcn_s_barrier();

    // ---- phase 3: MFMA h1/c1 ; stage Ah1(kt g+2) ; K-tile vmcnt ----
    if (g + 2 < NT) stageA(bc, g + 2, 1);
    __builtin_amdgcn_s_barrier();
    __builtin_amdgcn_s_setprio(1);
#pragma unroll
    for (int fr4 = 0; fr4 < 4; ++fr4)
#pragma unroll
      for (int fn2 = 0; fn2 < 2; ++fn2)
#pragma unroll
        for (int kk = 0; kk < 2; ++kk)
          acc[4 + fr4][2 + fn2] = MFMA16(a[fr4][kk], b1[fn2][kk], acc[4 + fr4][2 + fn2]);
    __builtin_amdgcn_s_setprio(0);
    if (g + 2 < NT)      asm volatile("s_waitcnt vmcnt(4)" ::: "memory");
    else if (g + 1 < NT) asm volatile("s_waitcnt vmcnt(0)" ::: "memory");
    __builtin_amdgcn_s_barrier();
  }
}

// ------------------------------- gemm1 (qkv) --------------------------------
// 1536 blocks; XCD swizzle: 6 n-tiles of one A panel co-XCD.

__global__ __launch_bounds__(512, 1) void gemm_qkv_k(
    const ushort* __restrict__ xb, const ushort* __restrict__ Wp,
    ushort* __restrict__ Qb, ushort* __restrict__ Kb, ushort* __restrict__ Vt) {
  __shared__ __align__(16) char lds[131072];
  f32x4 acc[8][4];
  const int Bid = blockIdx.x;
  const int xcd = Bid & 7, idx = Bid >> 3;
  const int nt = idx % 6, pl = idx / 6;         // pl 0..31
  const int m0 = ((pl << 3) + xcd) << 8;        // 256 m-tiles * 256
  const int n0 = nt << 8;
  gemm_nt_8phase(xb, Wp, 512, 512, 8, m0, n0, lds, acc);

  const int tid = threadIdx.x, w = tid >> 6, l = tid & 63;
  const int il = l & 15, kl = l >> 4;
  const int wm = w >> 2, wn = w & 3;
  const int kq = n0 >> 9;                       // block-uniform: 0=Q 1=K 2=V
  const int br = m0 >> 8, b = br >> 6, r = br & 63;   // one (b,r) per block

  if (kq < 2) {
    ushort* dstb = kq ? Kb : Qb;
#pragma unroll
    for (int fm = 0; fm < 8; ++fm)
#pragma unroll
      for (int fn = 0; fn < 4; ++fn) {
        int n = (n0 & 511) + (wn << 6) + (fn << 4) + il;
        int h = (n >> 6) & 7, d = n & 63;
#pragma unroll
        for (int j = 0; j < 4; ++j) {
          int i = (wm << 7) + (fm << 4) + (kl << 2) + j;
          size_t dst = ((size_t)((((b << 3) + h) << 8) + i) << 12) + (r << 6) + d;
          dstb[dst] = f2bf(acc[fm][fn][j]);     // lanes: 2B x16 contiguous in d
        }
      }
  } else {
#pragma unroll
    for (int fm = 0; fm < 8; ++fm)
#pragma unroll
      for (int fn = 0; fn < 4; ++fn) {
        int n = (n0 - 1024) + (wn << 6) + (fn << 4) + il;   // h*64+d
        int h = n >> 6, d = n & 63;
        int i0 = (wm << 7) + (fm << 4) + (kl << 2);
        size_t dst = (((size_t)((((b << 3) + h) << 12)) + (r << 6) + d) << 8) + i0;
        ushort4 pk; pk.x = f2bf(acc[fm][fn][0]); pk.y = f2bf(acc[fm][fn][1]);
        pk.z = f2bf(acc[fm][fn][2]); pk.w = f2bf(acc[fm][fn][3]);
        *reinterpret_cast<ushort4*>(&Vt[dst]) = pk;   // 4 consecutive i
      }
  }
}

// ------------------------------- gemm2 (out) --------------------------------
// 512 blocks; XCD swizzle; scalar f32 stores (lanes 4B x16 contiguous).

__global__ __launch_bounds__(512, 1) void gemm_out_k(
    const ushort* __restrict__ O2, const ushort* __restrict__ W0b,
    float* __restrict__ out) {
  __shared__ __align__(16) char lds[131072];
  f32x4 acc[8][4];
  const int Bid = blockIdx.x;
  const int xcd = Bid & 7, idx = Bid >> 3;
  const int nt = idx & 1, pl = idx >> 1;        // pl 0..31
  const int m0 = ((pl << 3) + xcd) << 8;
  const int n0 = nt << 8;
  gemm_nt_8phase(O2, W0b, 512, 512, 8, m0, n0, lds, acc);

  const int tid = threadIdx.x, w = tid >> 6, l = tid & 63;
  const int il = l & 15, kl = l >> 4;
  const int wm = w >> 2, wn = w & 3;
#pragma unroll
  for (int fm = 0; fm < 8; ++fm)
#pragma unroll
    for (int fn = 0; fn < 4; ++fn) {
      int n = n0 + (wn << 6) + (fn << 4) + il;
#pragma unroll
      for (int j = 0; j < 4; ++j) {
        int m = m0 + (wm << 7) + (fm << 4) + (kl << 2) + j;
        out[(size_t)m * 512 + n] = acc[fm][fn][j];
      }
    }
}

// ---------------------- gemm_s: S partials (split-K=8) ----------------------
// 256 blocks; bh = Bid&31 (8 ks-blocks of one bh co-XCD). Sp[bh*8+ks] fp32.

__global__ __launch_bounds__(512, 1) void gemm_s_k(
    const ushort* __restrict__ Qb, const ushort* __restrict__ Kb,
    float* __restrict__ Sp) {
  __shared__ __align__(16) char lds[131072];
  f32x4 acc[8][4];
  const int Bid = blockIdx.x;
  const int bh = Bid & 31, ks = Bid >> 5;       // ks 0..7
  const size_t base = ((size_t)bh << 20) + ((size_t)ks << 9);
  gemm_nt_8phase(Qb + base, Kb + base, 4096, 4096, 8, 0, 0, lds, acc);

  const int tid = threadIdx.x, w = tid >> 6, l = tid & 63;
  const int il = l & 15, kl = l >> 4;
  const int wm = w >> 2, wn = w & 3;
  float* o = Sp + ((size_t)((bh << 3) + ks) << 16);
#pragma unroll
  for (int fm = 0; fm < 8; ++fm)
#pragma unroll
    for (int fn = 0; fn < 4; ++fn) {
      int n = (wn << 6) + (fn << 4) + il;
#pragma unroll
      for (int j = 0; j < 4; ++j) {
        int m = (wm << 7) + (fm << 4) + (kl << 2) + j;
        o[(size_t)m * 256 + n] = acc[fm][fn][j];
      }
    }
}

// ------------------------- softmax (wave per row) ---------------------------

__global__ void softmax_k(const float* __restrict__ Sp, ushort* __restrict__ Pb) {
  const int w = threadIdx.x >> 6, l = threadIdx.x & 63;
  const int row = (blockIdx.x << 2) + w;        // 0..8191
  const int bh = row >> 8, i = row & 255;
  const float4* p0 = reinterpret_cast<const float4*>(
      Sp + (((size_t)bh << 3) << 16) + ((size_t)i << 8)) + l;
  float s0 = 0.f, s1 = 0.f, s2 = 0.f, s3 = 0.f;
#pragma unroll
  for (int ks = 0; ks < 8; ++ks) {
    float4 a = p0[(size_t)ks * 16384];
    s0 += a.x; s1 += a.y; s2 += a.z; s3 += a.w;
  }
  const float scale = 0.015625f;
  s0 *= scale; s1 *= scale; s2 *= scale; s3 *= scale;
  float m = fmaxf(fmaxf(s0, s1), fmaxf(s2, s3));
#pragma unroll
  for (int d2 = 1; d2 < 64; d2 <<= 1) m = fmaxf(m, __shfl_xor(m, d2));
  float e0 = __expf(s0 - m), e1 = __expf(s1 - m);
  float e2 = __expf(s2 - m), e3 = __expf(s3 - m);
  float sum = e0 + e1 + e2 + e3;
#pragma unroll
  for (int d2 = 1; d2 < 64; d2 <<= 1) sum += __shfl_xor(sum, d2);
  float r = 1.0f / sum;
  ushort4 p; p.x = f2bf(e0 * r); p.y = f2bf(e1 * r);
  p.z = f2bf(e2 * r); p.w = f2bf(e3 * r);
  reinterpret_cast<ushort4*>(Pb + ((size_t)bh << 16) + ((size_t)i << 8))[l] = p;
}

// ---------------------- gemm_pv: O = P V  (A=Vt, B=P) -----------------------
// 512 blocks; bh = Bid&31 co-XCD. M=4096 (rd), N=256, K=256 (NT=4).

__global__ __launch_bounds__(512, 1) void gemm_pv_k(
    const ushort* __restrict__ Vt, const ushort* __restrict__ Pb,
    ushort* __restrict__ O2) {
  __shared__ __align__(16) char lds[131072];
  f32x4 acc[8][4];
  const int Bid = blockIdx.x;
  const int bh = Bid & 31, mt = Bid >> 5;       // mt 0..15
  const int b = bh >> 3, h = bh & 7;
  const int m0 = mt << 8;
  gemm_nt_8phase(Vt + ((size_t)bh << 20), Pb + ((size_t)bh << 16),
                 256, 256, 4, m0, 0, lds, acc);

  const int tid = threadIdx.x, w = tid >> 6, l = tid & 63;
  const int il = l & 15, kl = l >> 4;
  const int wm = w >> 2, wn = w & 3;
#pragma unroll
  for (int fm = 0; fm < 8; ++fm) {
    int rd0 = m0 + (wm << 7) + (fm << 4) + (kl << 2);
    int r = rd0 >> 6, d0 = rd0 & 63;
#pragma unroll
    for (int fn = 0; fn < 4; ++fn) {
      int i = (wn << 6) + (fn << 4) + il;
      ushort4 pk; pk.x = f2bf(acc[fm][fn][0]); pk.y = f2bf(acc[fm][fn][1]);
      pk.z = f2bf(acc[fm][fn][2]); pk.w = f2bf(acc[fm][fn][3]);
      *reinterpret_cast<ushort4*>(
          O2 + ((size_t)((((b << 6) + r) << 8) + i) << 9) + (h << 6) + d0) = pk;
    }
  }
}

// ------------------------------- launcher -----------------------------------

extern "C" void kernel_launch(void* const* d_in, const int* in_sizes, int n_in,
                              void* d_out, int out_size, void* d_ws, size_t ws_size,
                              hipStream_t stream) {
  const float* x    = (const float*)d_in[0];
  const float* Wqkv = (const float*)d_in[1];
  const float* W0   = (const float*)d_in[2];
  float* out = (float*)d_out;

  char* ws = (char*)d_ws;
  ushort* xb  = (ushort*)(ws);                    // 67,108,864 B (-> Sp -> O2)
  ushort* Wp  = (ushort*)(ws + 67108864);         //  1,572,864
  ushort* W0b = (ushort*)(ws + 68681728);         //    524,288
  ushort* Qb  = (ushort*)(ws + 69206016);         // 67,108,864 (-> Pb)
  ushort* Kb  = (ushort*)(ws + 136314880);        // 67,108,864
  ushort* Vt  = (ushort*)(ws + 203423744);        // 67,108,864  -> total 270,532,608
  if (ws_size < 270532608ull) return;             // workspace too small: fail visibly

  cast_f32_to_bf16<<<2048, 256, 0, stream>>>(x, xb, 8388608);
  cast_f32_to_bf16<<<256, 256, 0, stream>>>(W0, W0b, 65536);
  permute_wqkv_k<<<1536, 128, 0, stream>>>(Wqkv, Wp);

  gemm_qkv_k<<<1536, 512, 0, stream>>>(xb, Wp, Qb, Kb, Vt);

  float*  Sp = (float*)xb;                        // xb dead after gemm1 (64 MB)
  ushort* Pb = Qb;                                // Qb dead after gemm_s (8.4 MB)
  ushort* O2 = xb;                                // Sp dead after softmax (64 MB)

  gemm_s_k<<<256, 512, 0, stream>>>(Qb, Kb, Sp);
  softmax_k<<<2048, 256, 0, stream>>>(Sp, Pb);
  gemm_pv_k<<<512, 512, 0, stream>>>(Vt, Pb, O2);

  gemm_out_k<<<512, 512, 0, stream>>>(O2, W0b, out);
}